// Round 2
// baseline (1235.622 us; speedup 1.0000x reference)
//
#include <hip/hip_runtime.h>

#define BB 2
#define NTOK 21952      // 28^3
#define CC 96
#define WD 784          // 28*28
#define NSR 343         // 7^3
#define SCALE 0.25f
#define LN_EPS 1e-5f

// ---------------------------------------------------------------------------
// K1: P[token][288] = x @ [lepe_lin | q1 | q2 | kv2]^T   (+ lepe bias on 0:96)
// ---------------------------------------------------------------------------
__global__ __launch_bounds__(320) void k_proj(
    const float* __restrict__ x, const float* __restrict__ lepe_w,
    const float* __restrict__ lepe_b, const float* __restrict__ q1_w,
    const float* __restrict__ q2_w, const float* __restrict__ kv2_w,
    float* __restrict__ P)
{
    __shared__ float xl[16 * 96];
    const int j = threadIdx.x;
    float wreg[96];
    float bias = 0.f;
    const float* wrow = nullptr;
    if (j < 96)        { wrow = lepe_w + j * 96; bias = lepe_b[j]; }
    else if (j < 144)  { wrow = q1_w + (j - 96) * 96; }
    else if (j < 192)  { wrow = q2_w + (j - 144) * 96; }
    else if (j < 288)  { wrow = kv2_w + (j - 192) * 96; }
    if (wrow) {
        const float4* w4 = (const float4*)wrow;
#pragma unroll
        for (int i = 0; i < 24; i++) {
            float4 v = w4[i];
            wreg[4 * i] = v.x; wreg[4 * i + 1] = v.y;
            wreg[4 * i + 2] = v.z; wreg[4 * i + 3] = v.w;
        }
    }
    const int base = blockIdx.x * 128;
    for (int chunk = 0; chunk < 128; chunk += 16) {
        const float4* xg = (const float4*)(x + (size_t)(base + chunk) * 96);
        for (int idx = threadIdx.x; idx < 384; idx += 320)
            ((float4*)xl)[idx] = xg[idx];
        __syncthreads();
        if (j < 288) {
            for (int t = 0; t < 16; t++) {
                const float4* xr = (const float4*)(xl + t * 96);
                float acc = bias;
#pragma unroll
                for (int c = 0; c < 24; c++) {
                    float4 v = xr[c];
                    acc += v.x * wreg[4 * c] + v.y * wreg[4 * c + 1] +
                           v.z * wreg[4 * c + 2] + v.w * wreg[4 * c + 3];
                }
                P[(size_t)(base + chunk + t) * 288 + j] = acc;
            }
        }
        __syncthreads();
    }
}

// ---------------------------------------------------------------------------
// K2: SR conv (4x4x4 stride 4) + bias + LN + GELU + kv1 -> k1/v1 [B][3][343][16]
// ---------------------------------------------------------------------------
__global__ __launch_bounds__(128) void k_sr(
    const float* __restrict__ x, const float* __restrict__ sr_w,
    const float* __restrict__ sr_b, const float* __restrict__ norm_g,
    const float* __restrict__ norm_b, const float* __restrict__ kv1_w,
    float* __restrict__ k1, float* __restrict__ v1)
{
    __shared__ float patchT[96][68];   // [ci][p], padded rows
    __shared__ float xs_s[96];
    __shared__ float gx[96];

    const int s = blockIdx.x % NSR, b = blockIdx.x / NSR;
    const int si = s / 49, sj = (s / 7) % 7, sk = s % 7;

    // stage the 64x96 patch, transposed to [ci][p]
    for (int idx = threadIdx.x; idx < 1536; idx += 128) {
        int p = idx / 24, cg = idx % 24;
        int a = p >> 4, q = (p >> 2) & 3, r = p & 3;
        int n = (4 * si + a) * WD + (4 * sj + q) * 28 + (4 * sk + r);
        const float4* xp = (const float4*)(x + ((size_t)b * NTOK + n) * 96);
        float4 v = xp[cg];
        patchT[cg * 4 + 0][p] = v.x;
        patchT[cg * 4 + 1][p] = v.y;
        patchT[cg * 4 + 2][p] = v.z;
        patchT[cg * 4 + 3][p] = v.w;
    }
    __syncthreads();

    const int co = threadIdx.x;
    float acc = 0.f;
    if (co < 96) {
        acc = sr_b[co];
        const float* wrow = sr_w + (size_t)co * 6144;
        for (int ci = 0; ci < 96; ci++) {
            const float4* pr4 = (const float4*)(&patchT[ci][0]);
            const float4* wr4 = (const float4*)(wrow + ci * 64);
#pragma unroll
            for (int g = 0; g < 16; g++) {
                float4 w = wr4[g];
                float4 a0 = pr4[g];
                acc += a0.x * w.x + a0.y * w.y + a0.z * w.z + a0.w * w.w;
            }
        }
        xs_s[co] = acc;
    }
    __syncthreads();
    if (co < 96) {
        float m = 0.f, m2 = 0.f;
        for (int c = 0; c < 96; c++) { float v = xs_s[c]; m += v; m2 += v * v; }
        m *= (1.f / 96.f);
        float var = m2 * (1.f / 96.f) - m * m;
        float t = (acc - m) * rsqrtf(var + LN_EPS) * norm_g[co] + norm_b[co];
        gx[co] = 0.5f * t * (1.f + erff(t * 0.70710678118654752f));
    }
    __syncthreads();
    if (co < 96) {
        const float4* w4 = (const float4*)(kv1_w + co * 96);
        float a2 = 0.f;
        const float4* g4 = (const float4*)gx;
#pragma unroll
        for (int c = 0; c < 24; c++) {
            float4 w = w4[c]; float4 g = g4[c];
            a2 += g.x * w.x + g.y * w.y + g.z * w.z + g.w * w.w;
        }
        int pair = co / 48, h = (co % 48) / 16, e = co % 16;
        float* dst = pair ? v1 : k1;
        dst[(((size_t)b * 3 + h) * NSR + s) * 16 + e] = a2;
    }
}

// ---------------------------------------------------------------------------
// attention row helper: one wave, q[16] vs K/V[343][17] in LDS
// ---------------------------------------------------------------------------
__device__ __forceinline__ void attn_row(
    const float* __restrict__ qg, const float (*kl)[17], const float (*vl)[17],
    int lane, float* __restrict__ yo)
{
    float qv[16];
    const float4* q4 = (const float4*)qg;
#pragma unroll
    for (int i = 0; i < 4; i++) {
        float4 a = q4[i];
        qv[4 * i] = a.x; qv[4 * i + 1] = a.y; qv[4 * i + 2] = a.z; qv[4 * i + 3] = a.w;
    }
    float sc[6];
#pragma unroll
    for (int i = 0; i < 6; i++) {
        int m = lane + (i << 6);
        float s = -1e30f;
        if (m < NSR) {
            s = 0.f;
#pragma unroll
            for (int e = 0; e < 16; e++) s += qv[e] * kl[m][e];
            s *= SCALE;
        }
        sc[i] = s;
    }
    float mx = sc[0];
#pragma unroll
    for (int i = 1; i < 6; i++) mx = fmaxf(mx, sc[i]);
#pragma unroll
    for (int off = 32; off; off >>= 1) mx = fmaxf(mx, __shfl_xor(mx, off, 64));
    float p[6]; float sm = 0.f;
#pragma unroll
    for (int i = 0; i < 6; i++) {
        int m = lane + (i << 6);
        p[i] = (m < NSR) ? __expf(sc[i] - mx) : 0.f;
        sm += p[i];
    }
#pragma unroll
    for (int off = 32; off; off >>= 1) sm += __shfl_xor(sm, off, 64);
    float inv = 1.f / sm;
    float o[16];
#pragma unroll
    for (int e = 0; e < 16; e++) o[e] = 0.f;
#pragma unroll
    for (int i = 0; i < 6; i++) {
        int m = lane + (i << 6);
        if (m < NSR) {
            float pi = p[i];
#pragma unroll
            for (int e = 0; e < 16; e++) o[e] += pi * vl[m][e];
        }
    }
#pragma unroll
    for (int off = 32; off; off >>= 1) {
#pragma unroll
        for (int e = 0; e < 16; e++) o[e] += __shfl_xor(o[e], off, 64);
    }
    if (lane == 0) {
        float4* y4 = (float4*)yo;
        y4[0] = make_float4(o[0] * inv, o[1] * inv, o[2] * inv, o[3] * inv);
        y4[1] = make_float4(o[4] * inv, o[5] * inv, o[6] * inv, o[7] * inv);
        y4[2] = make_float4(o[8] * inv, o[9] * inv, o[10] * inv, o[11] * inv);
        y4[3] = make_float4(o[12] * inv, o[13] * inv, o[14] * inv, o[15] * inv);
    }
}

// K3: branch-1 SR attention -> y[:, :, 0:48]
__global__ __launch_bounds__(256) void k_attn1(
    const float* __restrict__ P, const float* __restrict__ k1,
    const float* __restrict__ v1, float* __restrict__ y)
{
    __shared__ float kl[NSR][17];
    __shared__ float vl[NSR][17];
    const int bh = blockIdx.x;          // [0,6)
    const int b = bh / 3, h = bh % 3;
    const float* ks = k1 + (size_t)bh * NSR * 16;
    const float* vs = v1 + (size_t)bh * NSR * 16;
    for (int idx = threadIdx.x; idx < NSR * 16; idx += 256) {
        kl[idx >> 4][idx & 15] = ks[idx];
        vl[idx >> 4][idx & 15] = vs[idx];
    }
    __syncthreads();
    const int wave = threadIdx.x >> 6, lane = threadIdx.x & 63;
    const int tokbase = blockIdx.y * 256;
    for (int t = wave; t < 256; t += 4) {
        int n = tokbase + t;
        if (n < NTOK) {
            const float* qg = P + ((size_t)b * NTOK + n) * 288 + 96 + h * 16;
            float* yo = y + ((size_t)b * NTOK + n) * 96 + h * 16;
            attn_row(qg, kl, vl, lane, yo);
        }
    }
}

// K4: branch-2 windowed attention -> y[:, :, 48:96]
__global__ __launch_bounds__(256) void k_attn2(
    const float* __restrict__ P, float* __restrict__ y)
{
    __shared__ float kl[NSR][17];
    __shared__ float vl[NSR][17];
    const int pb = blockIdx.x >> 1, half = blockIdx.x & 1;
    const int b = pb / (3 * 64);
    const int rem = pb % (3 * 64);
    const int h = rem / 64, win = rem % 64;
    const int wh = win >> 4, ww = (win >> 2) & 3, wd = win & 3;
    const int h0 = wh * 7, w0 = ww * 7, d0 = wd * 7;

    for (int idx = threadIdx.x; idx < NSR * 16; idx += 256) {
        int m = idx >> 4, e = idx & 15;
        int a = m / 49, bb2 = (m / 7) % 7, cc2 = m % 7;
        int n = (h0 + a) * WD + (w0 + bb2) * 28 + (d0 + cc2);
        const float* src = P + ((size_t)b * NTOK + n) * 288 + 192 + h * 16;
        kl[m][e] = src[e];
        vl[m][e] = src[48 + e];
    }
    __syncthreads();
    const int wave = threadIdx.x >> 6, lane = threadIdx.x & 63;
    const int rowbeg = half ? 172 : 0;
    const int rowend = half ? NSR : 172;
    for (int r = rowbeg + wave; r < rowend; r += 4) {
        int a = r / 49, bb2 = (r / 7) % 7, cc2 = r % 7;
        int n = (h0 + a) * WD + (w0 + bb2) * 28 + (d0 + cc2);
        const float* qg = P + ((size_t)b * NTOK + n) * 288 + 144 + h * 16;
        float* yo = y + ((size_t)b * NTOK + n) * 96 + 48 + h * 16;
        attn_row(qg, kl, vl, lane, yo);
    }
}

// K5: LePE depthwise 3x3x3 conv over t = P[:,0:96]; y += lepe
__global__ __launch_bounds__(256) void k_lepe(
    const float* __restrict__ P, const float* __restrict__ cw,
    const float* __restrict__ cb, float* __restrict__ y)
{
    const int id = blockIdx.x * 256 + threadIdx.x;
    if (id >= BB * NTOK * CC) return;
    const int c = id % 96;
    const int n = (id / 96) % NTOK;
    const int b = id / (96 * NTOK);
    const int h = n / WD, w = (n / 28) % 28, d = n % 28;
    float wv[27];
#pragma unroll
    for (int i = 0; i < 27; i++) wv[i] = cw[c * 27 + i];
    float acc = cb[c];
#pragma unroll
    for (int p = 0; p < 3; p++) {
        int hh = h + p - 1;
        if (hh < 0 || hh >= 28) continue;
#pragma unroll
        for (int q = 0; q < 3; q++) {
            int wwi = w + q - 1;
            if (wwi < 0 || wwi >= 28) continue;
#pragma unroll
            for (int r = 0; r < 3; r++) {
                int dd = d + r - 1;
                if (dd < 0 || dd >= 28) continue;
                int nn = hh * WD + wwi * 28 + dd;
                acc += P[((size_t)b * NTOK + nn) * 288 + c] * wv[p * 9 + q * 3 + r];
            }
        }
    }
    y[id] += acc;
}

// K6: out = y @ proj_w^T + proj_b   (fp32 out)
__global__ __launch_bounds__(128) void k_out(
    const float* __restrict__ y, const float* __restrict__ proj_w,
    const float* __restrict__ proj_b, float* __restrict__ out)
{
    __shared__ float yl[1536];   // 16 tokens x 96
    const int j = threadIdx.x;
    float wreg[96]; float bias = 0.f;
    if (j < 96) {
        const float4* w4 = (const float4*)(proj_w + j * 96);
#pragma unroll
        for (int i = 0; i < 24; i++) {
            float4 v = w4[i];
            wreg[4 * i] = v.x; wreg[4 * i + 1] = v.y;
            wreg[4 * i + 2] = v.z; wreg[4 * i + 3] = v.w;
        }
        bias = proj_b[j];
    }
    const int base = blockIdx.x * 128;
    for (int chunk = 0; chunk < 128; chunk += 16) {
        const float4* yg4 = (const float4*)(y + (size_t)(base + chunk) * 96);
        for (int idx = threadIdx.x; idx < 384; idx += 128)
            ((float4*)yl)[idx] = yg4[idx];
        __syncthreads();
        if (j < 96) {
            for (int t = 0; t < 16; t++) {
                float acc = bias;
                const float4* xr = (const float4*)(&yl[t * 96]);
#pragma unroll
                for (int c4 = 0; c4 < 24; c4++) {
                    float4 xv = xr[c4];
                    acc += xv.x * wreg[4 * c4 + 0] + xv.y * wreg[4 * c4 + 1] +
                           xv.z * wreg[4 * c4 + 2] + xv.w * wreg[4 * c4 + 3];
                }
                out[(size_t)(base + chunk + t) * 96 + j] = acc;
            }
        }
        __syncthreads();
    }
}

extern "C" void kernel_launch(void* const* d_in, const int* in_sizes, int n_in,
                              void* d_out, int out_size, void* d_ws, size_t ws_size,
                              hipStream_t stream) {
    const float* x          = (const float*)d_in[0];
    const float* lepe_lin_w = (const float*)d_in[4];
    const float* lepe_lin_b = (const float*)d_in[5];
    const float* lepe_conv_w= (const float*)d_in[6];
    const float* lepe_conv_b= (const float*)d_in[7];
    const float* sr_w       = (const float*)d_in[8];
    const float* sr_b       = (const float*)d_in[9];
    const float* norm_g     = (const float*)d_in[10];
    const float* norm_b     = (const float*)d_in[11];
    const float* q1_w       = (const float*)d_in[12];
    const float* kv1_w      = (const float*)d_in[13];
    const float* q2_w       = (const float*)d_in[14];
    const float* kv2_w      = (const float*)d_in[15];
    const float* proj_w     = (const float*)d_in[16];
    const float* proj_b     = (const float*)d_in[17];

    float* P  = (float*)d_ws;                         // [B*N][288]
    float* k1 = P + (size_t)BB * NTOK * 288;          // [B][3][343][16]
    float* v1 = k1 + (size_t)BB * 3 * NSR * 16;
    float* y  = v1 + (size_t)BB * 3 * NSR * 16;       // [B*N][96]

    k_proj<<<343, 320, 0, stream>>>(x, lepe_lin_w, lepe_lin_b, q1_w, q2_w, kv2_w, P);
    k_sr<<<BB * NSR, 128, 0, stream>>>(x, sr_w, sr_b, norm_g, norm_b, kv1_w, k1, v1);
    k_attn1<<<dim3(6, 86), 256, 0, stream>>>(P, k1, v1, y);
    k_attn2<<<768, 256, 0, stream>>>(P, y);
    k_lepe<<<(BB * NTOK * CC + 255) / 256, 256, 0, stream>>>(P, lepe_conv_w, lepe_conv_b, y);
    k_out<<<343, 128, 0, stream>>>(y, proj_w, proj_b, (float*)d_out);
}

// Round 3
// 884.614 us; speedup vs baseline: 1.3968x; 1.3968x over previous
//
#include <hip/hip_runtime.h>

#define BB 2
#define NTOK 21952      // 28^3
#define CC 96
#define WD 784          // 28*28
#define NSR 343         // 7^3
#define SCALE 0.25f
#define LN_EPS 1e-5f

// ---------------------------------------------------------------------------
// K1: P[token][288] = x @ [lepe_lin | q1 | q2 | kv2]^T   (+ lepe bias on 0:96)
// ---------------------------------------------------------------------------
__global__ __launch_bounds__(320) void k_proj(
    const float* __restrict__ x, const float* __restrict__ lepe_w,
    const float* __restrict__ lepe_b, const float* __restrict__ q1_w,
    const float* __restrict__ q2_w, const float* __restrict__ kv2_w,
    float* __restrict__ P)
{
    __shared__ float xl[16 * 96];
    const int j = threadIdx.x;
    float wreg[96];
    float bias = 0.f;
    const float* wrow = nullptr;
    if (j < 96)        { wrow = lepe_w + j * 96; bias = lepe_b[j]; }
    else if (j < 144)  { wrow = q1_w + (j - 96) * 96; }
    else if (j < 192)  { wrow = q2_w + (j - 144) * 96; }
    else if (j < 288)  { wrow = kv2_w + (j - 192) * 96; }
    if (wrow) {
        const float4* w4 = (const float4*)wrow;
#pragma unroll
        for (int i = 0; i < 24; i++) {
            float4 v = w4[i];
            wreg[4 * i] = v.x; wreg[4 * i + 1] = v.y;
            wreg[4 * i + 2] = v.z; wreg[4 * i + 3] = v.w;
        }
    }
    const int base = blockIdx.x * 128;
    for (int chunk = 0; chunk < 128; chunk += 16) {
        const float4* xg = (const float4*)(x + (size_t)(base + chunk) * 96);
        for (int idx = threadIdx.x; idx < 384; idx += 320)
            ((float4*)xl)[idx] = xg[idx];
        __syncthreads();
        if (j < 288) {
            for (int t = 0; t < 16; t++) {
                const float4* xr = (const float4*)(xl + t * 96);
                float acc = bias;
#pragma unroll
                for (int c = 0; c < 24; c++) {
                    float4 v = xr[c];
                    acc += v.x * wreg[4 * c] + v.y * wreg[4 * c + 1] +
                           v.z * wreg[4 * c + 2] + v.w * wreg[4 * c + 3];
                }
                P[(size_t)(base + chunk + t) * 288 + j] = acc;
            }
        }
        __syncthreads();
    }
}

// ---------------------------------------------------------------------------
// K2: SR conv (4x4x4 stride 4) + bias + LN + GELU + kv1 -> k1/v1 [B][3][343][16]
// ---------------------------------------------------------------------------
__global__ __launch_bounds__(128) void k_sr(
    const float* __restrict__ x, const float* __restrict__ sr_w,
    const float* __restrict__ sr_b, const float* __restrict__ norm_g,
    const float* __restrict__ norm_b, const float* __restrict__ kv1_w,
    float* __restrict__ k1, float* __restrict__ v1)
{
    __shared__ float patchT[96][68];   // [ci][p], padded rows
    __shared__ float xs_s[96];
    __shared__ float gx[96];

    const int s = blockIdx.x % NSR, b = blockIdx.x / NSR;
    const int si = s / 49, sj = (s / 7) % 7, sk = s % 7;

    // stage the 64x96 patch, transposed to [ci][p]
    for (int idx = threadIdx.x; idx < 1536; idx += 128) {
        int p = idx / 24, cg = idx % 24;
        int a = p >> 4, q = (p >> 2) & 3, r = p & 3;
        int n = (4 * si + a) * WD + (4 * sj + q) * 28 + (4 * sk + r);
        const float4* xp = (const float4*)(x + ((size_t)b * NTOK + n) * 96);
        float4 v = xp[cg];
        patchT[cg * 4 + 0][p] = v.x;
        patchT[cg * 4 + 1][p] = v.y;
        patchT[cg * 4 + 2][p] = v.z;
        patchT[cg * 4 + 3][p] = v.w;
    }
    __syncthreads();

    const int co = threadIdx.x;
    float acc = 0.f;
    if (co < 96) {
        acc = sr_b[co];
        const float* wrow = sr_w + (size_t)co * 6144;
        for (int ci = 0; ci < 96; ci++) {
            const float4* pr4 = (const float4*)(&patchT[ci][0]);
            const float4* wr4 = (const float4*)(wrow + ci * 64);
#pragma unroll
            for (int g = 0; g < 16; g++) {
                float4 w = wr4[g];
                float4 a0 = pr4[g];
                acc += a0.x * w.x + a0.y * w.y + a0.z * w.z + a0.w * w.w;
            }
        }
        xs_s[co] = acc;
    }
    __syncthreads();
    if (co < 96) {
        float m = 0.f, m2 = 0.f;
        for (int c = 0; c < 96; c++) { float v = xs_s[c]; m += v; m2 += v * v; }
        m *= (1.f / 96.f);
        float var = m2 * (1.f / 96.f) - m * m;
        float t = (acc - m) * rsqrtf(var + LN_EPS) * norm_g[co] + norm_b[co];
        gx[co] = 0.5f * t * (1.f + erff(t * 0.70710678118654752f));
    }
    __syncthreads();
    if (co < 96) {
        const float4* w4 = (const float4*)(kv1_w + co * 96);
        float a2 = 0.f;
        const float4* g4 = (const float4*)gx;
#pragma unroll
        for (int c = 0; c < 24; c++) {
            float4 w = w4[c]; float4 g = g4[c];
            a2 += g.x * w.x + g.y * w.y + g.z * w.z + g.w * w.w;
        }
        int pair = co / 48, h = (co % 48) / 16, e = co % 16;
        float* dst = pair ? v1 : k1;
        dst[(((size_t)b * 3 + h) * NSR + s) * 16 + e] = a2;
    }
}

// ---------------------------------------------------------------------------
// helpers
// ---------------------------------------------------------------------------
__device__ __forceinline__ void ld16_g(const float* p, float* o) {
    const float4* p4 = (const float4*)p;
#pragma unroll
    for (int i = 0; i < 4; i++) {
        float4 v = p4[i];
        o[4 * i] = v.x; o[4 * i + 1] = v.y; o[4 * i + 2] = v.z; o[4 * i + 3] = v.w;
    }
}
__device__ __forceinline__ void st16_g(float* p, const float* o, float scl) {
    float4* p4 = (float4*)p;
#pragma unroll
    for (int i = 0; i < 4; i++)
        p4[i] = make_float4(o[4 * i] * scl, o[4 * i + 1] * scl,
                            o[4 * i + 2] * scl, o[4 * i + 3] * scl);
}

// ---------------------------------------------------------------------------
// K3: branch-1 SR attention -> y[:, :, 0:48]
// lane-per-query (2 queries/lane), sequential over 343 keys, LDS broadcast.
// ---------------------------------------------------------------------------
__global__ __launch_bounds__(256) void k_attn1(
    const float* __restrict__ P, const float* __restrict__ k1,
    const float* __restrict__ v1, float* __restrict__ y)
{
    __shared__ float kl[NSR * 16];
    __shared__ float vl[NSR * 16];
    const int bh = blockIdx.x;          // [0,6)
    const int b = bh / 3, h = bh % 3;
    const float4* ks = (const float4*)(k1 + (size_t)bh * NSR * 16);
    const float4* vs = (const float4*)(v1 + (size_t)bh * NSR * 16);
    for (int idx = threadIdx.x; idx < NSR * 4; idx += 256) {
        ((float4*)kl)[idx] = ks[idx];
        ((float4*)vl)[idx] = vs[idx];
    }
    __syncthreads();

    const int wave = threadIdx.x >> 6, lane = threadIdx.x & 63;
    const int n0 = blockIdx.y * 512 + wave * 128 + lane;   // always < NTOK
    const int n1 = n0 + 64;
    const bool v1ok = (n1 < NTOK);

    float q0[16], q1[16];
    ld16_g(P + ((size_t)b * NTOK + n0) * 288 + 96 + h * 16, q0);
    ld16_g(P + ((size_t)b * NTOK + (v1ok ? n1 : n0)) * 288 + 96 + h * 16, q1);

    float a0[16], a1[16];
#pragma unroll
    for (int e = 0; e < 16; e++) { a0[e] = 0.f; a1[e] = 0.f; }
    float l0 = 0.f, l1 = 0.f;

    const float4* k4 = (const float4*)kl;
    const float4* v4 = (const float4*)vl;
    for (int m = 0; m < NSR; m++) {
        float kk[16], vv[16];
#pragma unroll
        for (int i = 0; i < 4; i++) {
            float4 t = k4[4 * m + i];
            kk[4 * i] = t.x; kk[4 * i + 1] = t.y; kk[4 * i + 2] = t.z; kk[4 * i + 3] = t.w;
        }
#pragma unroll
        for (int i = 0; i < 4; i++) {
            float4 t = v4[4 * m + i];
            vv[4 * i] = t.x; vv[4 * i + 1] = t.y; vv[4 * i + 2] = t.z; vv[4 * i + 3] = t.w;
        }
        float s0 = 0.f, s1 = 0.f;
#pragma unroll
        for (int e = 0; e < 16; e++) { s0 += q0[e] * kk[e]; s1 += q1[e] * kk[e]; }
        float p0 = __expf(s0 * SCALE), p1 = __expf(s1 * SCALE);
        l0 += p0; l1 += p1;
#pragma unroll
        for (int e = 0; e < 16; e++) { a0[e] += p0 * vv[e]; a1[e] += p1 * vv[e]; }
    }
    st16_g(y + ((size_t)b * NTOK + n0) * 96 + h * 16, a0, 1.f / l0);
    if (v1ok)
        st16_g(y + ((size_t)b * NTOK + n1) * 96 + h * 16, a1, 1.f / l1);
}

// ---------------------------------------------------------------------------
// K4: branch-2 windowed attention -> y[:, :, 48:96]
// one block per (b,h,window); lane-per-query (2/lane), keys sequential.
// ---------------------------------------------------------------------------
__global__ __launch_bounds__(192) void k_attn2(
    const float* __restrict__ P, float* __restrict__ y)
{
    __shared__ float kl[NSR * 16];
    __shared__ float vl[NSR * 16];
    const int blk = blockIdx.x;               // [0, 384)
    const int b = blk / 192;
    const int rem = blk % 192;
    const int h = rem / 64, win = rem % 64;
    const int wh = win >> 4, ww = (win >> 2) & 3, wd = win & 3;
    const int h0 = wh * 7, w0 = ww * 7, d0 = wd * 7;

    for (int idx = threadIdx.x; idx < NSR * 4; idx += 192) {
        int m = idx >> 2, e4 = idx & 3;
        int a = m / 49, bw = (m / 7) % 7, cw = m % 7;
        int n = (h0 + a) * WD + (w0 + bw) * 28 + (d0 + cw);
        const float* src = P + ((size_t)b * NTOK + n) * 288 + 192 + h * 16 + e4 * 4;
        ((float4*)kl)[idx] = *(const float4*)src;
        ((float4*)vl)[idx] = *(const float4*)(src + 48);
    }
    __syncthreads();

    const int t0 = threadIdx.x;               // < 192 < 343
    const int t1 = t0 + 192;
    const bool v1ok = (t1 < NSR);

    int a0i = t0 / 49, b0i = (t0 / 7) % 7, c0i = t0 % 7;
    int n0 = (h0 + a0i) * WD + (w0 + b0i) * 28 + (d0 + c0i);
    int tt = v1ok ? t1 : t0;
    int a1i = tt / 49, b1i = (tt / 7) % 7, c1i = tt % 7;
    int n1 = (h0 + a1i) * WD + (w0 + b1i) * 28 + (d0 + c1i);

    float q0[16], q1[16];
    ld16_g(P + ((size_t)b * NTOK + n0) * 288 + 144 + h * 16, q0);
    ld16_g(P + ((size_t)b * NTOK + n1) * 288 + 144 + h * 16, q1);

    float a0[16], a1[16];
#pragma unroll
    for (int e = 0; e < 16; e++) { a0[e] = 0.f; a1[e] = 0.f; }
    float l0 = 0.f, l1 = 0.f;

    const float4* k4 = (const float4*)kl;
    const float4* v4 = (const float4*)vl;
    for (int m = 0; m < NSR; m++) {
        float kk[16], vv[16];
#pragma unroll
        for (int i = 0; i < 4; i++) {
            float4 t = k4[4 * m + i];
            kk[4 * i] = t.x; kk[4 * i + 1] = t.y; kk[4 * i + 2] = t.z; kk[4 * i + 3] = t.w;
        }
#pragma unroll
        for (int i = 0; i < 4; i++) {
            float4 t = v4[4 * m + i];
            vv[4 * i] = t.x; vv[4 * i + 1] = t.y; vv[4 * i + 2] = t.z; vv[4 * i + 3] = t.w;
        }
        float s0 = 0.f, s1 = 0.f;
#pragma unroll
        for (int e = 0; e < 16; e++) { s0 += q0[e] * kk[e]; s1 += q1[e] * kk[e]; }
        float p0 = __expf(s0 * SCALE), p1 = __expf(s1 * SCALE);
        l0 += p0; l1 += p1;
#pragma unroll
        for (int e = 0; e < 16; e++) { a0[e] += p0 * vv[e]; a1[e] += p1 * vv[e]; }
    }
    st16_g(y + ((size_t)b * NTOK + n0) * 96 + 48 + h * 16, a0, 1.f / l0);
    if (v1ok)
        st16_g(y + ((size_t)b * NTOK + n1) * 96 + 48 + h * 16, a1, 1.f / l1);
}

// K5: LePE depthwise 3x3x3 conv over t = P[:,0:96]; y += lepe
__global__ __launch_bounds__(256) void k_lepe(
    const float* __restrict__ P, const float* __restrict__ cw,
    const float* __restrict__ cb, float* __restrict__ y)
{
    const int id = blockIdx.x * 256 + threadIdx.x;
    if (id >= BB * NTOK * CC) return;
    const int c = id % 96;
    const int n = (id / 96) % NTOK;
    const int b = id / (96 * NTOK);
    const int h = n / WD, w = (n / 28) % 28, d = n % 28;
    float wv[27];
#pragma unroll
    for (int i = 0; i < 27; i++) wv[i] = cw[c * 27 + i];
    float acc = cb[c];
#pragma unroll
    for (int p = 0; p < 3; p++) {
        int hh = h + p - 1;
        if (hh < 0 || hh >= 28) continue;
#pragma unroll
        for (int q = 0; q < 3; q++) {
            int wwi = w + q - 1;
            if (wwi < 0 || wwi >= 28) continue;
#pragma unroll
            for (int r = 0; r < 3; r++) {
                int dd = d + r - 1;
                if (dd < 0 || dd >= 28) continue;
                int nn = hh * WD + wwi * 28 + dd;
                acc += P[((size_t)b * NTOK + nn) * 288 + c] * wv[p * 9 + q * 3 + r];
            }
        }
    }
    y[id] += acc;
}

// K6: out = y @ proj_w^T + proj_b   (fp32 out)
__global__ __launch_bounds__(128) void k_out(
    const float* __restrict__ y, const float* __restrict__ proj_w,
    const float* __restrict__ proj_b, float* __restrict__ out)
{
    __shared__ float yl[1536];   // 16 tokens x 96
    const int j = threadIdx.x;
    float wreg[96]; float bias = 0.f;
    if (j < 96) {
        const float4* w4 = (const float4*)(proj_w + j * 96);
#pragma unroll
        for (int i = 0; i < 24; i++) {
            float4 v = w4[i];
            wreg[4 * i] = v.x; wreg[4 * i + 1] = v.y;
            wreg[4 * i + 2] = v.z; wreg[4 * i + 3] = v.w;
        }
        bias = proj_b[j];
    }
    const int base = blockIdx.x * 128;
    for (int chunk = 0; chunk < 128; chunk += 16) {
        const float4* yg4 = (const float4*)(y + (size_t)(base + chunk) * 96);
        for (int idx = threadIdx.x; idx < 384; idx += 128)
            ((float4*)yl)[idx] = yg4[idx];
        __syncthreads();
        if (j < 96) {
            for (int t = 0; t < 16; t++) {
                float acc = bias;
                const float4* xr = (const float4*)(&yl[t * 96]);
#pragma unroll
                for (int c4 = 0; c4 < 24; c4++) {
                    float4 xv = xr[c4];
                    acc += xv.x * wreg[4 * c4 + 0] + xv.y * wreg[4 * c4 + 1] +
                           xv.z * wreg[4 * c4 + 2] + xv.w * wreg[4 * c4 + 3];
                }
                out[(size_t)(base + chunk + t) * 96 + j] = acc;
            }
        }
        __syncthreads();
    }
}

extern "C" void kernel_launch(void* const* d_in, const int* in_sizes, int n_in,
                              void* d_out, int out_size, void* d_ws, size_t ws_size,
                              hipStream_t stream) {
    const float* x          = (const float*)d_in[0];
    const float* lepe_lin_w = (const float*)d_in[4];
    const float* lepe_lin_b = (const float*)d_in[5];
    const float* lepe_conv_w= (const float*)d_in[6];
    const float* lepe_conv_b= (const float*)d_in[7];
    const float* sr_w       = (const float*)d_in[8];
    const float* sr_b       = (const float*)d_in[9];
    const float* norm_g     = (const float*)d_in[10];
    const float* norm_b     = (const float*)d_in[11];
    const float* q1_w       = (const float*)d_in[12];
    const float* kv1_w      = (const float*)d_in[13];
    const float* q2_w       = (const float*)d_in[14];
    const float* kv2_w      = (const float*)d_in[15];
    const float* proj_w     = (const float*)d_in[16];
    const float* proj_b     = (const float*)d_in[17];

    float* P  = (float*)d_ws;                         // [B*N][288]
    float* k1 = P + (size_t)BB * NTOK * 288;          // [B][3][343][16]
    float* v1 = k1 + (size_t)BB * 3 * NSR * 16;
    float* y  = v1 + (size_t)BB * 3 * NSR * 16;       // [B*N][96]

    k_proj<<<343, 320, 0, stream>>>(x, lepe_lin_w, lepe_lin_b, q1_w, q2_w, kv2_w, P);
    k_sr<<<BB * NSR, 128, 0, stream>>>(x, sr_w, sr_b, norm_g, norm_b, kv1_w, k1, v1);
    k_attn1<<<dim3(6, 43), 256, 0, stream>>>(P, k1, v1, y);
    k_attn2<<<384, 192, 0, stream>>>(P, y);
    k_lepe<<<(BB * NTOK * CC + 255) / 256, 256, 0, stream>>>(P, lepe_conv_w, lepe_conv_b, y);
    k_out<<<343, 128, 0, stream>>>(y, proj_w, proj_b, (float*)d_out);
}

// Round 4
// 628.514 us; speedup vs baseline: 1.9659x; 1.4075x over previous
//
#include <hip/hip_runtime.h>

#define BB 2
#define NTOK 21952      // 28^3
#define CC 96
#define WD 784          // 28*28
#define NSR 343         // 7^3
#define NSITE 686       // BB*NSR
#define SCALE 0.25f
#define LN_EPS 1e-5f

// ---------------------------------------------------------------------------
// K0: transpose sr_w [96][6144] -> Wt4[1536][96] (float4 over 4 consecutive k)
// ---------------------------------------------------------------------------
__global__ __launch_bounds__(256) void k_wt(
    const float* __restrict__ w, float4* __restrict__ Wt4)
{
    const int id = blockIdx.x * 256 + threadIdx.x;
    if (id >= 96 * 1536) return;
    const int co = id % 96, kbg = id / 96;
    const float4 v = *(const float4*)(w + (size_t)co * 6144 + 4 * kbg);
    Wt4[(size_t)kbg * 96 + co] = v;
}

// ---------------------------------------------------------------------------
// K1: P[token][288] = x @ [lepe_lin | q1 | q2 | kv2]^T   (+ lepe bias on 0:96)
// ---------------------------------------------------------------------------
__global__ __launch_bounds__(320) void k_proj(
    const float* __restrict__ x, const float* __restrict__ lepe_w,
    const float* __restrict__ lepe_b, const float* __restrict__ q1_w,
    const float* __restrict__ q2_w, const float* __restrict__ kv2_w,
    float* __restrict__ P)
{
    __shared__ float xl[16 * 96];
    const int j = threadIdx.x;
    float wreg[96];
    float bias = 0.f;
    const float* wrow = nullptr;
    if (j < 96)        { wrow = lepe_w + j * 96; bias = lepe_b[j]; }
    else if (j < 144)  { wrow = q1_w + (j - 96) * 96; }
    else if (j < 192)  { wrow = q2_w + (j - 144) * 96; }
    else if (j < 288)  { wrow = kv2_w + (j - 192) * 96; }
    if (wrow) {
        const float4* w4 = (const float4*)wrow;
#pragma unroll
        for (int i = 0; i < 24; i++) {
            float4 v = w4[i];
            wreg[4 * i] = v.x; wreg[4 * i + 1] = v.y;
            wreg[4 * i + 2] = v.z; wreg[4 * i + 3] = v.w;
        }
    }
    const int base = blockIdx.x * 64;
    for (int chunk = 0; chunk < 64; chunk += 16) {
        const float4* xg = (const float4*)(x + (size_t)(base + chunk) * 96);
        for (int idx = threadIdx.x; idx < 384; idx += 320)
            ((float4*)xl)[idx] = xg[idx];
        __syncthreads();
        if (j < 288) {
            for (int t = 0; t < 16; t++) {
                const float4* xr = (const float4*)(xl + t * 96);
                float acc = bias;
#pragma unroll
                for (int c = 0; c < 24; c++) {
                    float4 v = xr[c];
                    acc += v.x * wreg[4 * c] + v.y * wreg[4 * c + 1] +
                           v.z * wreg[4 * c + 2] + v.w * wreg[4 * c + 3];
                }
                P[(size_t)(base + chunk + t) * 288 + j] = acc;
            }
        }
        __syncthreads();
    }
}

// ---------------------------------------------------------------------------
// K2a: SR conv split-K GEMM. grid (86 site-groups x 16 k-splits), block 128.
// pa[site][ks][co] partial sums.
// ---------------------------------------------------------------------------
__global__ __launch_bounds__(128) void k_sr_a(
    const float* __restrict__ x, const float4* __restrict__ Wt4,
    float* __restrict__ pa)
{
    __shared__ float patch[8 * 384];     // [s][k_local], k_local = cl*64 + p
    const int sg = blockIdx.x, ks = blockIdx.y;
    const int ci0 = ks * 6;

    // stage 8 sites x 64 p x 6 ci
    for (int pr = threadIdx.x; pr < 512; pr += 128) {
        int s = pr >> 6, p = pr & 63;
        int s_g = sg * 8 + s; if (s_g > NSITE - 1) s_g = NSITE - 1;
        int b = s_g / NSR, sloc = s_g % NSR;
        int si = sloc / 49, sj = (sloc / 7) % 7, sk = sloc % 7;
        int a = p >> 4, q = (p >> 2) & 3, r = p & 3;
        int n = (4 * si + a) * WD + (4 * sj + q) * 28 + (4 * sk + r);
        const float2* xp = (const float2*)(x + ((size_t)b * NTOK + n) * 96 + ci0);
        float2 v0 = xp[0], v1 = xp[1], v2 = xp[2];
        int base = s * 384 + p;
        patch[base +   0] = v0.x; patch[base +  64] = v0.y;
        patch[base + 128] = v1.x; patch[base + 192] = v1.y;
        patch[base + 256] = v2.x; patch[base + 320] = v2.y;
    }
    __syncthreads();

    const int co = threadIdx.x;
    if (co >= 96) return;
    float acc[8];
#pragma unroll
    for (int s = 0; s < 8; s++) acc[s] = 0.f;
    const float4* p4 = (const float4*)patch;
    const float4* wb = Wt4 + (size_t)ks * 96 * 96 + co;
    for (int kb = 0; kb < 96; kb++) {
        float4 w = wb[(size_t)kb * 96];
#pragma unroll
        for (int s = 0; s < 8; s++) {
            float4 pv = p4[s * 96 + kb];
            acc[s] += pv.x * w.x + pv.y * w.y + pv.z * w.z + pv.w * w.w;
        }
    }
#pragma unroll
    for (int s = 0; s < 8; s++) {
        int s_g = sg * 8 + s;
        if (s_g < NSITE)
            pa[((size_t)s_g * 16 + ks) * 96 + co] = acc[s];
    }
}

// ---------------------------------------------------------------------------
// K2b: reduce 16 partials + bias + LN + GELU + kv1 -> k1/v1 [B][3][343][16]
// ---------------------------------------------------------------------------
__global__ __launch_bounds__(96) void k_sr_b(
    const float* __restrict__ pa, const float* __restrict__ sr_b,
    const float* __restrict__ norm_g, const float* __restrict__ norm_b,
    const float* __restrict__ kv1_w, float* __restrict__ k1,
    float* __restrict__ v1)
{
    __shared__ float xs_s[96];
    __shared__ float gx[96];
    const int s_g = blockIdx.x;
    const int b = s_g / NSR, s = s_g % NSR;
    const int co = threadIdx.x;

    const float* pp = pa + (size_t)s_g * 16 * 96 + co;
    float acc = sr_b[co];
#pragma unroll
    for (int ks = 0; ks < 16; ks++) acc += pp[ks * 96];
    xs_s[co] = acc;
    __syncthreads();

    float m = 0.f, m2 = 0.f;
    for (int c = 0; c < 96; c++) { float v = xs_s[c]; m += v; m2 += v * v; }
    m *= (1.f / 96.f);
    float var = m2 * (1.f / 96.f) - m * m;
    float t = (acc - m) * rsqrtf(var + LN_EPS) * norm_g[co] + norm_b[co];
    gx[co] = 0.5f * t * (1.f + erff(t * 0.70710678118654752f));
    __syncthreads();

    const float4* w4 = (const float4*)(kv1_w + co * 96);
    const float4* g4 = (const float4*)gx;
    float a2 = 0.f;
#pragma unroll
    for (int c = 0; c < 24; c++) {
        float4 w = w4[c]; float4 g = g4[c];
        a2 += g.x * w.x + g.y * w.y + g.z * w.z + g.w * w.w;
    }
    int pair = co / 48, h = (co % 48) / 16, e = co % 16;
    float* dst = pair ? v1 : k1;
    dst[(((size_t)b * 3 + h) * NSR + s) * 16 + e] = a2;
}

// ---------------------------------------------------------------------------
// helpers
// ---------------------------------------------------------------------------
__device__ __forceinline__ void ld16_g(const float* p, float* o) {
    const float4* p4 = (const float4*)p;
#pragma unroll
    for (int i = 0; i < 4; i++) {
        float4 v = p4[i];
        o[4 * i] = v.x; o[4 * i + 1] = v.y; o[4 * i + 2] = v.z; o[4 * i + 3] = v.w;
    }
}
__device__ __forceinline__ void st16_g(float* p, const float* o, float scl) {
    float4* p4 = (float4*)p;
#pragma unroll
    for (int i = 0; i < 4; i++)
        p4[i] = make_float4(o[4 * i] * scl, o[4 * i + 1] * scl,
                            o[4 * i + 2] * scl, o[4 * i + 3] * scl);
}

// ---------------------------------------------------------------------------
// K3: branch-1 SR attention -> y[:, :, 0:48]
// ---------------------------------------------------------------------------
__global__ __launch_bounds__(256) void k_attn1(
    const float* __restrict__ P, const float* __restrict__ k1,
    const float* __restrict__ v1, float* __restrict__ y)
{
    __shared__ float kl[NSR * 16];
    __shared__ float vl[NSR * 16];
    const int bh = blockIdx.x;          // [0,6)
    const int b = bh / 3, h = bh % 3;
    const float4* ks = (const float4*)(k1 + (size_t)bh * NSR * 16);
    const float4* vs = (const float4*)(v1 + (size_t)bh * NSR * 16);
    for (int idx = threadIdx.x; idx < NSR * 4; idx += 256) {
        ((float4*)kl)[idx] = ks[idx];
        ((float4*)vl)[idx] = vs[idx];
    }
    __syncthreads();

    const int wave = threadIdx.x >> 6, lane = threadIdx.x & 63;
    const int n0 = blockIdx.y * 512 + wave * 128 + lane;
    const int n1 = n0 + 64;
    const bool v1ok = (n1 < NTOK);

    float q0[16], q1[16];
    ld16_g(P + ((size_t)b * NTOK + n0) * 288 + 96 + h * 16, q0);
    ld16_g(P + ((size_t)b * NTOK + (v1ok ? n1 : n0)) * 288 + 96 + h * 16, q1);

    float a0[16], a1[16];
#pragma unroll
    for (int e = 0; e < 16; e++) { a0[e] = 0.f; a1[e] = 0.f; }
    float l0 = 0.f, l1 = 0.f;

    const float4* k4 = (const float4*)kl;
    const float4* v4 = (const float4*)vl;
    for (int m = 0; m < NSR; m++) {
        float kk[16], vv[16];
#pragma unroll
        for (int i = 0; i < 4; i++) {
            float4 t = k4[4 * m + i];
            kk[4 * i] = t.x; kk[4 * i + 1] = t.y; kk[4 * i + 2] = t.z; kk[4 * i + 3] = t.w;
        }
#pragma unroll
        for (int i = 0; i < 4; i++) {
            float4 t = v4[4 * m + i];
            vv[4 * i] = t.x; vv[4 * i + 1] = t.y; vv[4 * i + 2] = t.z; vv[4 * i + 3] = t.w;
        }
        float s0 = 0.f, s1 = 0.f;
#pragma unroll
        for (int e = 0; e < 16; e++) { s0 += q0[e] * kk[e]; s1 += q1[e] * kk[e]; }
        float p0 = __expf(s0 * SCALE), p1 = __expf(s1 * SCALE);
        l0 += p0; l1 += p1;
#pragma unroll
        for (int e = 0; e < 16; e++) { a0[e] += p0 * vv[e]; a1[e] += p1 * vv[e]; }
    }
    st16_g(y + ((size_t)b * NTOK + n0) * 96 + h * 16, a0, 1.f / l0);
    if (v1ok)
        st16_g(y + ((size_t)b * NTOK + n1) * 96 + h * 16, a1, 1.f / l1);
}

// ---------------------------------------------------------------------------
// K4: branch-2 windowed attention -> y[:, :, 48:96]
// ---------------------------------------------------------------------------
__global__ __launch_bounds__(192) void k_attn2(
    const float* __restrict__ P, float* __restrict__ y)
{
    __shared__ float kl[NSR * 16];
    __shared__ float vl[NSR * 16];
    const int blk = blockIdx.x;               // [0, 384)
    const int b = blk / 192;
    const int rem = blk % 192;
    const int h = rem / 64, win = rem % 64;
    const int wh = win >> 4, ww = (win >> 2) & 3, wd = win & 3;
    const int h0 = wh * 7, w0 = ww * 7, d0 = wd * 7;

    for (int idx = threadIdx.x; idx < NSR * 4; idx += 192) {
        int m = idx >> 2, e4 = idx & 3;
        int a = m / 49, bw = (m / 7) % 7, cw = m % 7;
        int n = (h0 + a) * WD + (w0 + bw) * 28 + (d0 + cw);
        const float* src = P + ((size_t)b * NTOK + n) * 288 + 192 + h * 16 + e4 * 4;
        ((float4*)kl)[idx] = *(const float4*)src;
        ((float4*)vl)[idx] = *(const float4*)(src + 48);
    }
    __syncthreads();

    const int t0 = threadIdx.x;
    const int t1 = t0 + 192;
    const bool v1ok = (t1 < NSR);

    int a0i = t0 / 49, b0i = (t0 / 7) % 7, c0i = t0 % 7;
    int n0 = (h0 + a0i) * WD + (w0 + b0i) * 28 + (d0 + c0i);
    int tt = v1ok ? t1 : t0;
    int a1i = tt / 49, b1i = (tt / 7) % 7, c1i = tt % 7;
    int n1 = (h0 + a1i) * WD + (w0 + b1i) * 28 + (d0 + c1i);

    float q0[16], q1[16];
    ld16_g(P + ((size_t)b * NTOK + n0) * 288 + 144 + h * 16, q0);
    ld16_g(P + ((size_t)b * NTOK + n1) * 288 + 144 + h * 16, q1);

    float a0[16], a1[16];
#pragma unroll
    for (int e = 0; e < 16; e++) { a0[e] = 0.f; a1[e] = 0.f; }
    float l0 = 0.f, l1 = 0.f;

    const float4* k4 = (const float4*)kl;
    const float4* v4 = (const float4*)vl;
    for (int m = 0; m < NSR; m++) {
        float kk[16], vv[16];
#pragma unroll
        for (int i = 0; i < 4; i++) {
            float4 t = k4[4 * m + i];
            kk[4 * i] = t.x; kk[4 * i + 1] = t.y; kk[4 * i + 2] = t.z; kk[4 * i + 3] = t.w;
        }
#pragma unroll
        for (int i = 0; i < 4; i++) {
            float4 t = v4[4 * m + i];
            vv[4 * i] = t.x; vv[4 * i + 1] = t.y; vv[4 * i + 2] = t.z; vv[4 * i + 3] = t.w;
        }
        float s0 = 0.f, s1 = 0.f;
#pragma unroll
        for (int e = 0; e < 16; e++) { s0 += q0[e] * kk[e]; s1 += q1[e] * kk[e]; }
        float p0 = __expf(s0 * SCALE), p1 = __expf(s1 * SCALE);
        l0 += p0; l1 += p1;
#pragma unroll
        for (int e = 0; e < 16; e++) { a0[e] += p0 * vv[e]; a1[e] += p1 * vv[e]; }
    }
    st16_g(y + ((size_t)b * NTOK + n0) * 96 + 48 + h * 16, a0, 1.f / l0);
    if (v1ok)
        st16_g(y + ((size_t)b * NTOK + n1) * 96 + 48 + h * 16, a1, 1.f / l1);
}

// K5: LePE depthwise 3x3x3 conv over t = P[:,0:96]; y += lepe
__global__ __launch_bounds__(256) void k_lepe(
    const float* __restrict__ P, const float* __restrict__ cw,
    const float* __restrict__ cb, float* __restrict__ y)
{
    const int id = blockIdx.x * 256 + threadIdx.x;
    if (id >= BB * NTOK * CC) return;
    const int c = id % 96;
    const int n = (id / 96) % NTOK;
    const int b = id / (96 * NTOK);
    const int h = n / WD, w = (n / 28) % 28, d = n % 28;
    float wv[27];
#pragma unroll
    for (int i = 0; i < 27; i++) wv[i] = cw[c * 27 + i];
    float acc = cb[c];
#pragma unroll
    for (int p = 0; p < 3; p++) {
        int hh = h + p - 1;
        if (hh < 0 || hh >= 28) continue;
#pragma unroll
        for (int q = 0; q < 3; q++) {
            int wwi = w + q - 1;
            if (wwi < 0 || wwi >= 28) continue;
#pragma unroll
            for (int r = 0; r < 3; r++) {
                int dd = d + r - 1;
                if (dd < 0 || dd >= 28) continue;
                int nn = hh * WD + wwi * 28 + dd;
                acc += P[((size_t)b * NTOK + nn) * 288 + c] * wv[p * 9 + q * 3 + r];
            }
        }
    }
    y[id] += acc;
}

// K6: out = y @ proj_w^T + proj_b   (fp32 out)
__global__ __launch_bounds__(128) void k_out(
    const float* __restrict__ y, const float* __restrict__ proj_w,
    const float* __restrict__ proj_b, float* __restrict__ out)
{
    __shared__ float yl[1536];   // 16 tokens x 96
    const int j = threadIdx.x;
    float wreg[96]; float bias = 0.f;
    if (j < 96) {
        const float4* w4 = (const float4*)(proj_w + j * 96);
#pragma unroll
        for (int i = 0; i < 24; i++) {
            float4 v = w4[i];
            wreg[4 * i] = v.x; wreg[4 * i + 1] = v.y;
            wreg[4 * i + 2] = v.z; wreg[4 * i + 3] = v.w;
        }
        bias = proj_b[j];
    }
    const int base = blockIdx.x * 64;
    for (int chunk = 0; chunk < 64; chunk += 16) {
        const float4* yg4 = (const float4*)(y + (size_t)(base + chunk) * 96);
        for (int idx = threadIdx.x; idx < 384; idx += 128)
            ((float4*)yl)[idx] = yg4[idx];
        __syncthreads();
        if (j < 96) {
            for (int t = 0; t < 16; t++) {
                float acc = bias;
                const float4* xr = (const float4*)(&yl[t * 96]);
#pragma unroll
                for (int c4 = 0; c4 < 24; c4++) {
                    float4 xv = xr[c4];
                    acc += xv.x * wreg[4 * c4 + 0] + xv.y * wreg[4 * c4 + 1] +
                           xv.z * wreg[4 * c4 + 2] + xv.w * wreg[4 * c4 + 3];
                }
                out[(size_t)(base + chunk + t) * 96 + j] = acc;
            }
        }
        __syncthreads();
    }
}

extern "C" void kernel_launch(void* const* d_in, const int* in_sizes, int n_in,
                              void* d_out, int out_size, void* d_ws, size_t ws_size,
                              hipStream_t stream) {
    const float* x          = (const float*)d_in[0];
    const float* lepe_lin_w = (const float*)d_in[4];
    const float* lepe_lin_b = (const float*)d_in[5];
    const float* lepe_conv_w= (const float*)d_in[6];
    const float* lepe_conv_b= (const float*)d_in[7];
    const float* sr_w       = (const float*)d_in[8];
    const float* sr_b       = (const float*)d_in[9];
    const float* norm_g     = (const float*)d_in[10];
    const float* norm_b     = (const float*)d_in[11];
    const float* q1_w       = (const float*)d_in[12];
    const float* kv1_w      = (const float*)d_in[13];
    const float* q2_w       = (const float*)d_in[14];
    const float* kv2_w      = (const float*)d_in[15];
    const float* proj_w     = (const float*)d_in[16];
    const float* proj_b     = (const float*)d_in[17];

    float* P   = (float*)d_ws;                        // [B*N][288]
    float* k1  = P + (size_t)BB * NTOK * 288;         // [B][3][343][16]
    float* v1  = k1 + (size_t)BB * 3 * NSR * 16;
    float* y   = v1 + (size_t)BB * 3 * NSR * 16;      // [B*N][96]
    float* pa  = y + (size_t)BB * NTOK * 96;          // [686][16][96]
    float* Wt  = pa + (size_t)NSITE * 16 * 96;        // [1536][96] float4

    k_wt<<<576, 256, 0, stream>>>(sr_w, (float4*)Wt);
    k_proj<<<686, 320, 0, stream>>>(x, lepe_lin_w, lepe_lin_b, q1_w, q2_w, kv2_w, P);
    k_sr_a<<<dim3(86, 16), 128, 0, stream>>>(x, (const float4*)Wt, pa);
    k_sr_b<<<NSITE, 96, 0, stream>>>(pa, sr_b, norm_g, norm_b, kv1_w, k1, v1);
    k_attn1<<<dim3(6, 43), 256, 0, stream>>>(P, k1, v1, y);
    k_attn2<<<384, 192, 0, stream>>>(P, y);
    k_lepe<<<(BB * NTOK * CC + 255) / 256, 256, 0, stream>>>(P, lepe_conv_w, lepe_conv_b, y);
    k_out<<<686, 128, 0, stream>>>(y, proj_w, proj_b, (float*)d_out);
}

// Round 5
// 505.980 us; speedup vs baseline: 2.4420x; 1.2422x over previous
//
#include <hip/hip_runtime.h>

#define BB 2
#define NTOK 21952      // 28^3
#define CC 96
#define WD 784          // 28*28
#define NSR 343         // 7^3
#define NSITE 686       // BB*NSR
#define SCALE 0.25f
#define LN_EPS 1e-5f

// ---------------------------------------------------------------------------
// K0: transpose sr_w [96][6144] -> Wt4[1536][96] (float4 over 4 consecutive k)
// ---------------------------------------------------------------------------
__global__ __launch_bounds__(256) void k_wt(
    const float* __restrict__ w, float4* __restrict__ Wt4)
{
    const int id = blockIdx.x * 256 + threadIdx.x;
    if (id >= 96 * 1536) return;
    const int co = id % 96, kbg = id / 96;
    const float4 v = *(const float4*)(w + (size_t)co * 6144 + 4 * kbg);
    Wt4[(size_t)kbg * 96 + co] = v;
}

// ---------------------------------------------------------------------------
// K1: P[token][288] = x @ [lepe_lin | q1 | q2 | kv2]^T  (+ lepe bias on 0:96)
// register-tiled GEMM: block = 64 tok x 48 j, thread = 4x4, K=96.
// ---------------------------------------------------------------------------
__global__ __launch_bounds__(192) void k_proj(
    const float* __restrict__ x, const float* __restrict__ lepe_w,
    const float* __restrict__ lepe_b, const float* __restrict__ q1_w,
    const float* __restrict__ q2_w, const float* __restrict__ kv2_w,
    float* __restrict__ P)
{
    __shared__ float xT[96][68];   // [k][t], padded row 272B (16B aligned)
    __shared__ float wT[96][52];   // [k][j], padded row 208B (16B aligned)

    const int base = blockIdx.x * 64;
    const int j0 = blockIdx.y * 48;

    // stage x tile transposed: 64 tok x 24 k-quads
    for (int it = threadIdx.x; it < 1536; it += 192) {
        int cq = it % 24, t = it / 24;
        float4 v = *(const float4*)(x + (size_t)(base + t) * 96 + cq * 4);
        xT[cq * 4 + 0][t] = v.x; xT[cq * 4 + 1][t] = v.y;
        xT[cq * 4 + 2][t] = v.z; xT[cq * 4 + 3][t] = v.w;
    }
    // stage weight tile transposed: 48 j x 24 k-quads
    for (int it = threadIdx.x; it < 1152; it += 192) {
        int cq = it % 24, jl = it / 24;
        int jg = j0 + jl;
        const float* wrow;
        if (jg < 96)       wrow = lepe_w + jg * 96;
        else if (jg < 144) wrow = q1_w + (jg - 96) * 96;
        else if (jg < 192) wrow = q2_w + (jg - 144) * 96;
        else               wrow = kv2_w + (jg - 192) * 96;
        float4 v = *(const float4*)(wrow + cq * 4);
        wT[cq * 4 + 0][jl] = v.x; wT[cq * 4 + 1][jl] = v.y;
        wT[cq * 4 + 2][jl] = v.z; wT[cq * 4 + 3][jl] = v.w;
    }
    __syncthreads();

    const int tq = threadIdx.x & 15;        // token quad
    const int jq = threadIdx.x >> 4;        // j quad (0..11)
    float acc[4][4];
#pragma unroll
    for (int i = 0; i < 4; i++)
#pragma unroll
        for (int jj = 0; jj < 4; jj++) acc[i][jj] = 0.f;

    for (int c = 0; c < 96; c++) {
        float4 xv = *(const float4*)(&xT[c][tq * 4]);
        float4 wv = *(const float4*)(&wT[c][jq * 4]);
        float xa[4] = {xv.x, xv.y, xv.z, xv.w};
        float wa[4] = {wv.x, wv.y, wv.z, wv.w};
#pragma unroll
        for (int i = 0; i < 4; i++)
#pragma unroll
            for (int jj = 0; jj < 4; jj++) acc[i][jj] += xa[i] * wa[jj];
    }

    float bias[4];
#pragma unroll
    for (int jj = 0; jj < 4; jj++) {
        int jg = j0 + jq * 4 + jj;
        bias[jj] = (jg < 96) ? lepe_b[jg] : 0.f;
    }
#pragma unroll
    for (int i = 0; i < 4; i++) {
        int t = base + tq * 4 + i;
        float4 o = make_float4(acc[i][0] + bias[0], acc[i][1] + bias[1],
                               acc[i][2] + bias[2], acc[i][3] + bias[3]);
        *(float4*)(P + (size_t)t * 288 + j0 + jq * 4) = o;
    }
}

// ---------------------------------------------------------------------------
// K2a: SR conv split-K GEMM. grid (86 site-groups x 16 k-splits), block 128.
// ---------------------------------------------------------------------------
__global__ __launch_bounds__(128) void k_sr_a(
    const float* __restrict__ x, const float4* __restrict__ Wt4,
    float* __restrict__ pa)
{
    __shared__ float patch[8 * 384];     // [s][k_local]
    const int sg = blockIdx.x, ks = blockIdx.y;
    const int ci0 = ks * 6;

    for (int pr = threadIdx.x; pr < 512; pr += 128) {
        int s = pr >> 6, p = pr & 63;
        int s_g = sg * 8 + s; if (s_g > NSITE - 1) s_g = NSITE - 1;
        int b = s_g / NSR, sloc = s_g % NSR;
        int si = sloc / 49, sj = (sloc / 7) % 7, sk = sloc % 7;
        int a = p >> 4, q = (p >> 2) & 3, r = p & 3;
        int n = (4 * si + a) * WD + (4 * sj + q) * 28 + (4 * sk + r);
        const float2* xp = (const float2*)(x + ((size_t)b * NTOK + n) * 96 + ci0);
        float2 v0 = xp[0], v1 = xp[1], v2 = xp[2];
        int base = s * 384 + p;
        patch[base +   0] = v0.x; patch[base +  64] = v0.y;
        patch[base + 128] = v1.x; patch[base + 192] = v1.y;
        patch[base + 256] = v2.x; patch[base + 320] = v2.y;
    }
    __syncthreads();

    const int co = threadIdx.x;
    if (co >= 96) return;
    float acc[8];
#pragma unroll
    for (int s = 0; s < 8; s++) acc[s] = 0.f;
    const float4* p4 = (const float4*)patch;
    const float4* wb = Wt4 + (size_t)ks * 96 * 96 + co;
    for (int kb = 0; kb < 96; kb++) {
        float4 w = wb[(size_t)kb * 96];
#pragma unroll
        for (int s = 0; s < 8; s++) {
            float4 pv = p4[s * 96 + kb];
            acc[s] += pv.x * w.x + pv.y * w.y + pv.z * w.z + pv.w * w.w;
        }
    }
#pragma unroll
    for (int s = 0; s < 8; s++) {
        int s_g = sg * 8 + s;
        if (s_g < NSITE)
            pa[((size_t)s_g * 16 + ks) * 96 + co] = acc[s];
    }
}

// ---------------------------------------------------------------------------
// K2b: reduce 16 partials + bias + LN + GELU + kv1 -> k1/v1 [B][3][343][16]
// ---------------------------------------------------------------------------
__global__ __launch_bounds__(96) void k_sr_b(
    const float* __restrict__ pa, const float* __restrict__ sr_b,
    const float* __restrict__ norm_g, const float* __restrict__ norm_b,
    const float* __restrict__ kv1_w, float* __restrict__ k1,
    float* __restrict__ v1)
{
    __shared__ float xs_s[96];
    __shared__ float gx[96];
    const int s_g = blockIdx.x;
    const int b = s_g / NSR, s = s_g % NSR;
    const int co = threadIdx.x;

    const float* pp = pa + (size_t)s_g * 16 * 96 + co;
    float acc = sr_b[co];
#pragma unroll
    for (int ks = 0; ks < 16; ks++) acc += pp[ks * 96];
    xs_s[co] = acc;
    __syncthreads();

    float m = 0.f, m2 = 0.f;
    for (int c = 0; c < 96; c++) { float v = xs_s[c]; m += v; m2 += v * v; }
    m *= (1.f / 96.f);
    float var = m2 * (1.f / 96.f) - m * m;
    float t = (acc - m) * rsqrtf(var + LN_EPS) * norm_g[co] + norm_b[co];
    gx[co] = 0.5f * t * (1.f + erff(t * 0.70710678118654752f));
    __syncthreads();

    const float4* w4 = (const float4*)(kv1_w + co * 96);
    const float4* g4 = (const float4*)gx;
    float a2 = 0.f;
#pragma unroll
    for (int c = 0; c < 24; c++) {
        float4 w = w4[c]; float4 g = g4[c];
        a2 += g.x * w.x + g.y * w.y + g.z * w.z + g.w * w.w;
    }
    int pair = co / 48, h = (co % 48) / 16, e = co % 16;
    float* dst = pair ? v1 : k1;
    dst[(((size_t)b * 3 + h) * NSR + s) * 16 + e] = a2;
}

// ---------------------------------------------------------------------------
// helpers
// ---------------------------------------------------------------------------
__device__ __forceinline__ void ld16_g(const float* p, float* o) {
    const float4* p4 = (const float4*)p;
#pragma unroll
    for (int i = 0; i < 4; i++) {
        float4 v = p4[i];
        o[4 * i] = v.x; o[4 * i + 1] = v.y; o[4 * i + 2] = v.z; o[4 * i + 3] = v.w;
    }
}
__device__ __forceinline__ void st16_g(float* p, const float* o, float scl) {
    float4* p4 = (float4*)p;
#pragma unroll
    for (int i = 0; i < 4; i++)
        p4[i] = make_float4(o[4 * i] * scl, o[4 * i + 1] * scl,
                            o[4 * i + 2] * scl, o[4 * i + 3] * scl);
}

// ---------------------------------------------------------------------------
// K3: branch-1 SR attention -> y[:, :, 0:48]
// ---------------------------------------------------------------------------
__global__ __launch_bounds__(256) void k_attn1(
    const float* __restrict__ P, const float* __restrict__ k1,
    const float* __restrict__ v1, float* __restrict__ y)
{
    __shared__ float kl[NSR * 16];
    __shared__ float vl[NSR * 16];
    const int bh = blockIdx.x;          // [0,6)
    const int b = bh / 3, h = bh % 3;
    const float4* ks = (const float4*)(k1 + (size_t)bh * NSR * 16);
    const float4* vs = (const float4*)(v1 + (size_t)bh * NSR * 16);
    for (int idx = threadIdx.x; idx < NSR * 4; idx += 256) {
        ((float4*)kl)[idx] = ks[idx];
        ((float4*)vl)[idx] = vs[idx];
    }
    __syncthreads();

    const int wave = threadIdx.x >> 6, lane = threadIdx.x & 63;
    const int n0 = blockIdx.y * 512 + wave * 128 + lane;
    const int n1 = n0 + 64;
    const bool v1ok = (n1 < NTOK);

    float q0[16], q1[16];
    ld16_g(P + ((size_t)b * NTOK + n0) * 288 + 96 + h * 16, q0);
    ld16_g(P + ((size_t)b * NTOK + (v1ok ? n1 : n0)) * 288 + 96 + h * 16, q1);

    float a0[16], a1[16];
#pragma unroll
    for (int e = 0; e < 16; e++) { a0[e] = 0.f; a1[e] = 0.f; }
    float l0 = 0.f, l1 = 0.f;

    const float4* k4 = (const float4*)kl;
    const float4* v4 = (const float4*)vl;
    for (int m = 0; m < NSR; m++) {
        float kk[16], vv[16];
#pragma unroll
        for (int i = 0; i < 4; i++) {
            float4 t = k4[4 * m + i];
            kk[4 * i] = t.x; kk[4 * i + 1] = t.y; kk[4 * i + 2] = t.z; kk[4 * i + 3] = t.w;
        }
#pragma unroll
        for (int i = 0; i < 4; i++) {
            float4 t = v4[4 * m + i];
            vv[4 * i] = t.x; vv[4 * i + 1] = t.y; vv[4 * i + 2] = t.z; vv[4 * i + 3] = t.w;
        }
        float s0 = 0.f, s1 = 0.f;
#pragma unroll
        for (int e = 0; e < 16; e++) { s0 += q0[e] * kk[e]; s1 += q1[e] * kk[e]; }
        float p0 = __expf(s0 * SCALE), p1 = __expf(s1 * SCALE);
        l0 += p0; l1 += p1;
#pragma unroll
        for (int e = 0; e < 16; e++) { a0[e] += p0 * vv[e]; a1[e] += p1 * vv[e]; }
    }
    st16_g(y + ((size_t)b * NTOK + n0) * 96 + h * 16, a0, 1.f / l0);
    if (v1ok)
        st16_g(y + ((size_t)b * NTOK + n1) * 96 + h * 16, a1, 1.f / l1);
}

// ---------------------------------------------------------------------------
// K4: branch-2 windowed attention -> y[:, :, 48:96]
// ---------------------------------------------------------------------------
__global__ __launch_bounds__(192) void k_attn2(
    const float* __restrict__ P, float* __restrict__ y)
{
    __shared__ float kl[NSR * 16];
    __shared__ float vl[NSR * 16];
    const int blk = blockIdx.x;               // [0, 384)
    const int b = blk / 192;
    const int rem = blk % 192;
    const int h = rem / 64, win = rem % 64;
    const int wh = win >> 4, ww = (win >> 2) & 3, wd = win & 3;
    const int h0 = wh * 7, w0 = ww * 7, d0 = wd * 7;

    for (int idx = threadIdx.x; idx < NSR * 4; idx += 192) {
        int m = idx >> 2, e4 = idx & 3;
        int a = m / 49, bw = (m / 7) % 7, cw = m % 7;
        int n = (h0 + a) * WD + (w0 + bw) * 28 + (d0 + cw);
        const float* src = P + ((size_t)b * NTOK + n) * 288 + 192 + h * 16 + e4 * 4;
        ((float4*)kl)[idx] = *(const float4*)src;
        ((float4*)vl)[idx] = *(const float4*)(src + 48);
    }
    __syncthreads();

    const int t0 = threadIdx.x;
    const int t1 = t0 + 192;
    const bool v1ok = (t1 < NSR);

    int a0i = t0 / 49, b0i = (t0 / 7) % 7, c0i = t0 % 7;
    int n0 = (h0 + a0i) * WD + (w0 + b0i) * 28 + (d0 + c0i);
    int tt = v1ok ? t1 : t0;
    int a1i = tt / 49, b1i = (tt / 7) % 7, c1i = tt % 7;
    int n1 = (h0 + a1i) * WD + (w0 + b1i) * 28 + (d0 + c1i);

    float q0[16], q1[16];
    ld16_g(P + ((size_t)b * NTOK + n0) * 288 + 144 + h * 16, q0);
    ld16_g(P + ((size_t)b * NTOK + n1) * 288 + 144 + h * 16, q1);

    float a0[16], a1[16];
#pragma unroll
    for (int e = 0; e < 16; e++) { a0[e] = 0.f; a1[e] = 0.f; }
    float l0 = 0.f, l1 = 0.f;

    const float4* k4 = (const float4*)kl;
    const float4* v4 = (const float4*)vl;
    for (int m = 0; m < NSR; m++) {
        float kk[16], vv[16];
#pragma unroll
        for (int i = 0; i < 4; i++) {
            float4 t = k4[4 * m + i];
            kk[4 * i] = t.x; kk[4 * i + 1] = t.y; kk[4 * i + 2] = t.z; kk[4 * i + 3] = t.w;
        }
#pragma unroll
        for (int i = 0; i < 4; i++) {
            float4 t = v4[4 * m + i];
            vv[4 * i] = t.x; vv[4 * i + 1] = t.y; vv[4 * i + 2] = t.z; vv[4 * i + 3] = t.w;
        }
        float s0 = 0.f, s1 = 0.f;
#pragma unroll
        for (int e = 0; e < 16; e++) { s0 += q0[e] * kk[e]; s1 += q1[e] * kk[e]; }
        float p0 = __expf(s0 * SCALE), p1 = __expf(s1 * SCALE);
        l0 += p0; l1 += p1;
#pragma unroll
        for (int e = 0; e < 16; e++) { a0[e] += p0 * vv[e]; a1[e] += p1 * vv[e]; }
    }
    st16_g(y + ((size_t)b * NTOK + n0) * 96 + 48 + h * 16, a0, 1.f / l0);
    if (v1ok)
        st16_g(y + ((size_t)b * NTOK + n1) * 96 + 48 + h * 16, a1, 1.f / l1);
}

// K5: LePE depthwise 3x3x3 conv over t = P[:,0:96]; y += lepe
__global__ __launch_bounds__(256) void k_lepe(
    const float* __restrict__ P, const float* __restrict__ cw,
    const float* __restrict__ cb, float* __restrict__ y)
{
    const int id = blockIdx.x * 256 + threadIdx.x;
    if (id >= BB * NTOK * CC) return;
    const int c = id % 96;
    const int n = (id / 96) % NTOK;
    const int b = id / (96 * NTOK);
    const int h = n / WD, w = (n / 28) % 28, d = n % 28;
    float wv[27];
#pragma unroll
    for (int i = 0; i < 27; i++) wv[i] = cw[c * 27 + i];
    float acc = cb[c];
#pragma unroll
    for (int p = 0; p < 3; p++) {
        int hh = h + p - 1;
        if (hh < 0 || hh >= 28) continue;
#pragma unroll
        for (int q = 0; q < 3; q++) {
            int wwi = w + q - 1;
            if (wwi < 0 || wwi >= 28) continue;
#pragma unroll
            for (int r = 0; r < 3; r++) {
                int dd = d + r - 1;
                if (dd < 0 || dd >= 28) continue;
                int nn = hh * WD + wwi * 28 + dd;
                acc += P[((size_t)b * NTOK + nn) * 288 + c] * wv[p * 9 + q * 3 + r];
            }
        }
    }
    y[id] += acc;
}

// ---------------------------------------------------------------------------
// K6: out = y @ proj_w^T + proj_b  — register-tiled GEMM, 64 tok x 48 j tile
// ---------------------------------------------------------------------------
__global__ __launch_bounds__(192) void k_out(
    const float* __restrict__ y, const float* __restrict__ proj_w,
    const float* __restrict__ proj_b, float* __restrict__ out)
{
    __shared__ float xT[96][68];
    __shared__ float wT[96][52];

    const int base = blockIdx.x * 64;
    const int j0 = blockIdx.y * 48;

    for (int it = threadIdx.x; it < 1536; it += 192) {
        int cq = it % 24, t = it / 24;
        float4 v = *(const float4*)(y + (size_t)(base + t) * 96 + cq * 4);
        xT[cq * 4 + 0][t] = v.x; xT[cq * 4 + 1][t] = v.y;
        xT[cq * 4 + 2][t] = v.z; xT[cq * 4 + 3][t] = v.w;
    }
    for (int it = threadIdx.x; it < 1152; it += 192) {
        int cq = it % 24, jl = it / 24;
        float4 v = *(const float4*)(proj_w + (size_t)(j0 + jl) * 96 + cq * 4);
        wT[cq * 4 + 0][jl] = v.x; wT[cq * 4 + 1][jl] = v.y;
        wT[cq * 4 + 2][jl] = v.z; wT[cq * 4 + 3][jl] = v.w;
    }
    __syncthreads();

    const int tq = threadIdx.x & 15;
    const int jq = threadIdx.x >> 4;
    float acc[4][4];
#pragma unroll
    for (int i = 0; i < 4; i++)
#pragma unroll
        for (int jj = 0; jj < 4; jj++) acc[i][jj] = 0.f;

    for (int c = 0; c < 96; c++) {
        float4 xv = *(const float4*)(&xT[c][tq * 4]);
        float4 wv = *(const float4*)(&wT[c][jq * 4]);
        float xa[4] = {xv.x, xv.y, xv.z, xv.w};
        float wa[4] = {wv.x, wv.y, wv.z, wv.w};
#pragma unroll
        for (int i = 0; i < 4; i++)
#pragma unroll
            for (int jj = 0; jj < 4; jj++) acc[i][jj] += xa[i] * wa[jj];
    }

    float4 bias = *(const float4*)(proj_b + j0 + jq * 4);
#pragma unroll
    for (int i = 0; i < 4; i++) {
        int t = base + tq * 4 + i;
        float4 o = make_float4(acc[i][0] + bias.x, acc[i][1] + bias.y,
                               acc[i][2] + bias.z, acc[i][3] + bias.w);
        *(float4*)(out + (size_t)t * 96 + j0 + jq * 4) = o;
    }
}

extern "C" void kernel_launch(void* const* d_in, const int* in_sizes, int n_in,
                              void* d_out, int out_size, void* d_ws, size_t ws_size,
                              hipStream_t stream) {
    const float* x          = (const float*)d_in[0];
    const float* lepe_lin_w = (const float*)d_in[4];
    const float* lepe_lin_b = (const float*)d_in[5];
    const float* lepe_conv_w= (const float*)d_in[6];
    const float* lepe_conv_b= (const float*)d_in[7];
    const float* sr_w       = (const float*)d_in[8];
    const float* sr_b       = (const float*)d_in[9];
    const float* norm_g     = (const float*)d_in[10];
    const float* norm_b     = (const float*)d_in[11];
    const float* q1_w       = (const float*)d_in[12];
    const float* kv1_w      = (const float*)d_in[13];
    const float* q2_w       = (const float*)d_in[14];
    const float* kv2_w      = (const float*)d_in[15];
    const float* proj_w     = (const float*)d_in[16];
    const float* proj_b     = (const float*)d_in[17];

    float* P   = (float*)d_ws;                        // [B*N][288]
    float* k1  = P + (size_t)BB * NTOK * 288;         // [B][3][343][16]
    float* v1  = k1 + (size_t)BB * 3 * NSR * 16;
    float* y   = v1 + (size_t)BB * 3 * NSR * 16;      // [B*N][96]
    float* pa  = y + (size_t)BB * NTOK * 96;          // [686][16][96]
    float* Wt  = pa + (size_t)NSITE * 16 * 96;        // [1536][96] float4

    k_wt<<<576, 256, 0, stream>>>(sr_w, (float4*)Wt);
    k_proj<<<dim3(686, 6), 192, 0, stream>>>(x, lepe_lin_w, lepe_lin_b, q1_w, q2_w, kv2_w, P);
    k_sr_a<<<dim3(86, 16), 128, 0, stream>>>(x, (const float4*)Wt, pa);
    k_sr_b<<<NSITE, 96, 0, stream>>>(pa, sr_b, norm_g, norm_b, kv1_w, k1, v1);
    k_attn1<<<dim3(6, 43), 256, 0, stream>>>(P, k1, v1, y);
    k_attn2<<<384, 192, 0, stream>>>(P, y);
    k_lepe<<<(BB * NTOK * CC + 255) / 256, 256, 0, stream>>>(P, lepe_conv_w, lepe_conv_b, y);
    k_out<<<dim3(686, 2), 192, 0, stream>>>(y, proj_w, proj_b, (float*)d_out);
}

// Round 6
// 481.447 us; speedup vs baseline: 2.5665x; 1.0510x over previous
//
#include <hip/hip_runtime.h>

#define BB 2
#define NTOK 21952      // 28^3
#define CC 96
#define WD 784          // 28*28
#define NSR 343         // 7^3
#define NSITE 686       // BB*NSR
#define SCALE 0.25f
#define LN_EPS 1e-5f

// ---------------------------------------------------------------------------
// K0: transpose sr_w [96][6144] -> Wt4[1536][96] (float4 over 4 consecutive k)
// ---------------------------------------------------------------------------
__global__ __launch_bounds__(256) void k_wt(
    const float* __restrict__ w, float4* __restrict__ Wt4)
{
    const int id = blockIdx.x * 256 + threadIdx.x;
    if (id >= 96 * 1536) return;
    const int co = id % 96, kbg = id / 96;
    const float4 v = *(const float4*)(w + (size_t)co * 6144 + 4 * kbg);
    Wt4[(size_t)kbg * 96 + co] = v;
}

// ---------------------------------------------------------------------------
// K1: P[token][288] = x @ [lepe_lin | q1 | q2 | kv2]^T  (+ lepe bias on 0:96)
// register-tiled GEMM: block = 64 tok x 48 j, thread = 4x4, K=96.
// ---------------------------------------------------------------------------
__global__ __launch_bounds__(192) void k_proj(
    const float* __restrict__ x, const float* __restrict__ lepe_w,
    const float* __restrict__ lepe_b, const float* __restrict__ q1_w,
    const float* __restrict__ q2_w, const float* __restrict__ kv2_w,
    float* __restrict__ P)
{
    __shared__ float xT[96][68];   // [k][t]
    __shared__ float wT[96][52];   // [k][j]

    const int base = blockIdx.x * 64;
    const int j0 = blockIdx.y * 48;

    for (int it = threadIdx.x; it < 1536; it += 192) {
        int cq = it % 24, t = it / 24;
        float4 v = *(const float4*)(x + (size_t)(base + t) * 96 + cq * 4);
        xT[cq * 4 + 0][t] = v.x; xT[cq * 4 + 1][t] = v.y;
        xT[cq * 4 + 2][t] = v.z; xT[cq * 4 + 3][t] = v.w;
    }
    for (int it = threadIdx.x; it < 1152; it += 192) {
        int cq = it % 24, jl = it / 24;
        int jg = j0 + jl;
        const float* wrow;
        if (jg < 96)       wrow = lepe_w + jg * 96;
        else if (jg < 144) wrow = q1_w + (jg - 96) * 96;
        else if (jg < 192) wrow = q2_w + (jg - 144) * 96;
        else               wrow = kv2_w + (jg - 192) * 96;
        float4 v = *(const float4*)(wrow + cq * 4);
        wT[cq * 4 + 0][jl] = v.x; wT[cq * 4 + 1][jl] = v.y;
        wT[cq * 4 + 2][jl] = v.z; wT[cq * 4 + 3][jl] = v.w;
    }
    __syncthreads();

    const int tq = threadIdx.x & 15;
    const int jq = threadIdx.x >> 4;
    float acc[4][4];
#pragma unroll
    for (int i = 0; i < 4; i++)
#pragma unroll
        for (int jj = 0; jj < 4; jj++) acc[i][jj] = 0.f;

    for (int c = 0; c < 96; c++) {
        float4 xv = *(const float4*)(&xT[c][tq * 4]);
        float4 wv = *(const float4*)(&wT[c][jq * 4]);
        float xa[4] = {xv.x, xv.y, xv.z, xv.w};
        float wa[4] = {wv.x, wv.y, wv.z, wv.w};
#pragma unroll
        for (int i = 0; i < 4; i++)
#pragma unroll
            for (int jj = 0; jj < 4; jj++) acc[i][jj] += xa[i] * wa[jj];
    }

    float bias[4];
#pragma unroll
    for (int jj = 0; jj < 4; jj++) {
        int jg = j0 + jq * 4 + jj;
        bias[jj] = (jg < 96) ? lepe_b[jg] : 0.f;
    }
#pragma unroll
    for (int i = 0; i < 4; i++) {
        int t = base + tq * 4 + i;
        float4 o = make_float4(acc[i][0] + bias[0], acc[i][1] + bias[1],
                               acc[i][2] + bias[2], acc[i][3] + bias[3]);
        *(float4*)(P + (size_t)t * 288 + j0 + jq * 4) = o;
    }
}

// ---------------------------------------------------------------------------
// K2a: SR conv split-K GEMM. grid (86 site-groups x 16 k-splits), block 128.
// ---------------------------------------------------------------------------
__global__ __launch_bounds__(128) void k_sr_a(
    const float* __restrict__ x, const float4* __restrict__ Wt4,
    float* __restrict__ pa)
{
    __shared__ float patch[8 * 384];
    const int sg = blockIdx.x, ks = blockIdx.y;
    const int ci0 = ks * 6;

    for (int pr = threadIdx.x; pr < 512; pr += 128) {
        int s = pr >> 6, p = pr & 63;
        int s_g = sg * 8 + s; if (s_g > NSITE - 1) s_g = NSITE - 1;
        int b = s_g / NSR, sloc = s_g % NSR;
        int si = sloc / 49, sj = (sloc / 7) % 7, sk = sloc % 7;
        int a = p >> 4, q = (p >> 2) & 3, r = p & 3;
        int n = (4 * si + a) * WD + (4 * sj + q) * 28 + (4 * sk + r);
        const float2* xp = (const float2*)(x + ((size_t)b * NTOK + n) * 96 + ci0);
        float2 v0 = xp[0], v1 = xp[1], v2 = xp[2];
        int base = s * 384 + p;
        patch[base +   0] = v0.x; patch[base +  64] = v0.y;
        patch[base + 128] = v1.x; patch[base + 192] = v1.y;
        patch[base + 256] = v2.x; patch[base + 320] = v2.y;
    }
    __syncthreads();

    const int co = threadIdx.x;
    if (co >= 96) return;
    float acc[8];
#pragma unroll
    for (int s = 0; s < 8; s++) acc[s] = 0.f;
    const float4* p4 = (const float4*)patch;
    const float4* wb = Wt4 + (size_t)ks * 96 * 96 + co;
    for (int kb = 0; kb < 96; kb++) {
        float4 w = wb[(size_t)kb * 96];
#pragma unroll
        for (int s = 0; s < 8; s++) {
            float4 pv = p4[s * 96 + kb];
            acc[s] += pv.x * w.x + pv.y * w.y + pv.z * w.z + pv.w * w.w;
        }
    }
#pragma unroll
    for (int s = 0; s < 8; s++) {
        int s_g = sg * 8 + s;
        if (s_g < NSITE)
            pa[((size_t)s_g * 16 + ks) * 96 + co] = acc[s];
    }
}

// ---------------------------------------------------------------------------
// K2b: reduce 16 partials + bias + LN + GELU + kv1 -> k1/v1 [B][3][343][16]
// ---------------------------------------------------------------------------
__global__ __launch_bounds__(96) void k_sr_b(
    const float* __restrict__ pa, const float* __restrict__ sr_b,
    const float* __restrict__ norm_g, const float* __restrict__ norm_b,
    const float* __restrict__ kv1_w, float* __restrict__ k1,
    float* __restrict__ v1)
{
    __shared__ float xs_s[96];
    __shared__ float gx[96];
    const int s_g = blockIdx.x;
    const int b = s_g / NSR, s = s_g % NSR;
    const int co = threadIdx.x;

    const float* pp = pa + (size_t)s_g * 16 * 96 + co;
    float acc = sr_b[co];
#pragma unroll
    for (int ks = 0; ks < 16; ks++) acc += pp[ks * 96];
    xs_s[co] = acc;
    __syncthreads();

    float m = 0.f, m2 = 0.f;
    for (int c = 0; c < 96; c++) { float v = xs_s[c]; m += v; m2 += v * v; }
    m *= (1.f / 96.f);
    float var = m2 * (1.f / 96.f) - m * m;
    float t = (acc - m) * rsqrtf(var + LN_EPS) * norm_g[co] + norm_b[co];
    gx[co] = 0.5f * t * (1.f + erff(t * 0.70710678118654752f));
    __syncthreads();

    const float4* w4 = (const float4*)(kv1_w + co * 96);
    const float4* g4 = (const float4*)gx;
    float a2 = 0.f;
#pragma unroll
    for (int c = 0; c < 24; c++) {
        float4 w = w4[c]; float4 g = g4[c];
        a2 += g.x * w.x + g.y * w.y + g.z * w.z + g.w * w.w;
    }
    int pair = co / 48, h = (co % 48) / 16, e = co % 16;
    float* dst = pair ? v1 : k1;
    dst[(((size_t)b * 3 + h) * NSR + s) * 16 + e] = a2;
}

// ---------------------------------------------------------------------------
// helpers
// ---------------------------------------------------------------------------
__device__ __forceinline__ void ld16_g(const float* p, float* o) {
    const float4* p4 = (const float4*)p;
#pragma unroll
    for (int i = 0; i < 4; i++) {
        float4 v = p4[i];
        o[4 * i] = v.x; o[4 * i + 1] = v.y; o[4 * i + 2] = v.z; o[4 * i + 3] = v.w;
    }
}
__device__ __forceinline__ void st16_g(float* p, const float* o, float scl) {
    float4* p4 = (float4*)p;
#pragma unroll
    for (int i = 0; i < 4; i++)
        p4[i] = make_float4(o[4 * i] * scl, o[4 * i + 1] * scl,
                            o[4 * i + 2] * scl, o[4 * i + 3] * scl);
}

// ---------------------------------------------------------------------------
// K3: branch-1 SR attention -> y[:, :, 0:48]
// 1 query/thread, grid (6 bh x 86 tiles), 256 threads.
// ---------------------------------------------------------------------------
__global__ __launch_bounds__(256) void k_attn1(
    const float* __restrict__ P, const float* __restrict__ k1,
    const float* __restrict__ v1, float* __restrict__ y)
{
    __shared__ float kl[NSR * 16];
    __shared__ float vl[NSR * 16];
    const int bh = blockIdx.x;
    const int b = bh / 3, h = bh % 3;
    const float4* ks = (const float4*)(k1 + (size_t)bh * NSR * 16);
    const float4* vs = (const float4*)(v1 + (size_t)bh * NSR * 16);
    for (int idx = threadIdx.x; idx < NSR * 4; idx += 256) {
        ((float4*)kl)[idx] = ks[idx];
        ((float4*)vl)[idx] = vs[idx];
    }
    __syncthreads();

    const int n0 = blockIdx.y * 256 + threadIdx.x;
    const bool ok = (n0 < NTOK);
    const int nq = ok ? n0 : (NTOK - 1);

    float q0[16];
    ld16_g(P + ((size_t)b * NTOK + nq) * 288 + 96 + h * 16, q0);

    float a0[16];
#pragma unroll
    for (int e = 0; e < 16; e++) a0[e] = 0.f;
    float l0 = 0.f;

    const float4* k4 = (const float4*)kl;
    const float4* v4 = (const float4*)vl;
    for (int m = 0; m < NSR; m++) {
        float kk[16], vv[16];
#pragma unroll
        for (int i = 0; i < 4; i++) {
            float4 t = k4[4 * m + i];
            kk[4 * i] = t.x; kk[4 * i + 1] = t.y; kk[4 * i + 2] = t.z; kk[4 * i + 3] = t.w;
        }
#pragma unroll
        for (int i = 0; i < 4; i++) {
            float4 t = v4[4 * m + i];
            vv[4 * i] = t.x; vv[4 * i + 1] = t.y; vv[4 * i + 2] = t.z; vv[4 * i + 3] = t.w;
        }
        float s0 = 0.f;
#pragma unroll
        for (int e = 0; e < 16; e++) s0 += q0[e] * kk[e];
        float p0 = __expf(s0 * SCALE);
        l0 += p0;
#pragma unroll
        for (int e = 0; e < 16; e++) a0[e] += p0 * vv[e];
    }
    if (ok)
        st16_g(y + ((size_t)b * NTOK + n0) * 96 + h * 16, a0, 1.f / l0);
}

// ---------------------------------------------------------------------------
// K4: branch-2 windowed attention -> y[:, :, 48:96]
// grid 768 = (b,h,win) x 2 query-halves, 192 threads, 1 query/thread.
// ---------------------------------------------------------------------------
__global__ __launch_bounds__(192) void k_attn2(
    const float* __restrict__ P, float* __restrict__ y)
{
    __shared__ float kl[NSR * 16];
    __shared__ float vl[NSR * 16];
    const int pb = blockIdx.x >> 1, half = blockIdx.x & 1;
    const int b = pb / 192;
    const int rem = pb % 192;
    const int h = rem / 64, win = rem % 64;
    const int wh = win >> 4, ww = (win >> 2) & 3, wd = win & 3;
    const int h0 = wh * 7, w0 = ww * 7, d0 = wd * 7;

    for (int idx = threadIdx.x; idx < NSR * 4; idx += 192) {
        int m = idx >> 2, e4 = idx & 3;
        int a = m / 49, bw = (m / 7) % 7, cw = m % 7;
        int n = (h0 + a) * WD + (w0 + bw) * 28 + (d0 + cw);
        const float* src = P + ((size_t)b * NTOK + n) * 288 + 192 + h * 16 + e4 * 4;
        ((float4*)kl)[idx] = *(const float4*)src;
        ((float4*)vl)[idx] = *(const float4*)(src + 48);
    }
    __syncthreads();

    const int t0 = half * 172 + threadIdx.x;
    const int rowend = half ? NSR : 172;
    const bool ok = (t0 < rowend);
    const int tq = ok ? t0 : 0;

    int a0i = tq / 49, b0i = (tq / 7) % 7, c0i = tq % 7;
    int n0 = (h0 + a0i) * WD + (w0 + b0i) * 28 + (d0 + c0i);

    float q0[16];
    ld16_g(P + ((size_t)b * NTOK + n0) * 288 + 144 + h * 16, q0);

    float a0[16];
#pragma unroll
    for (int e = 0; e < 16; e++) a0[e] = 0.f;
    float l0 = 0.f;

    const float4* k4 = (const float4*)kl;
    const float4* v4 = (const float4*)vl;
    for (int m = 0; m < NSR; m++) {
        float kk[16], vv[16];
#pragma unroll
        for (int i = 0; i < 4; i++) {
            float4 t = k4[4 * m + i];
            kk[4 * i] = t.x; kk[4 * i + 1] = t.y; kk[4 * i + 2] = t.z; kk[4 * i + 3] = t.w;
        }
#pragma unroll
        for (int i = 0; i < 4; i++) {
            float4 t = v4[4 * m + i];
            vv[4 * i] = t.x; vv[4 * i + 1] = t.y; vv[4 * i + 2] = t.z; vv[4 * i + 3] = t.w;
        }
        float s0 = 0.f;
#pragma unroll
        for (int e = 0; e < 16; e++) s0 += q0[e] * kk[e];
        float p0 = __expf(s0 * SCALE);
        l0 += p0;
#pragma unroll
        for (int e = 0; e < 16; e++) a0[e] += p0 * vv[e];
    }
    if (ok)
        st16_g(y + ((size_t)b * NTOK + n0) * 96 + 48 + h * 16, a0, 1.f / l0);
}

// K5: LePE depthwise 3x3x3 conv over t = P[:,0:96]; y += lepe
__global__ __launch_bounds__(256) void k_lepe(
    const float* __restrict__ P, const float* __restrict__ cw,
    const float* __restrict__ cb, float* __restrict__ y)
{
    const int id = blockIdx.x * 256 + threadIdx.x;
    if (id >= BB * NTOK * CC) return;
    const int c = id % 96;
    const int n = (id / 96) % NTOK;
    const int b = id / (96 * NTOK);
    const int h = n / WD, w = (n / 28) % 28, d = n % 28;
    float wv[27];
#pragma unroll
    for (int i = 0; i < 27; i++) wv[i] = cw[c * 27 + i];
    float acc = cb[c];
#pragma unroll
    for (int p = 0; p < 3; p++) {
        int hh = h + p - 1;
        if (hh < 0 || hh >= 28) continue;
#pragma unroll
        for (int q = 0; q < 3; q++) {
            int wwi = w + q - 1;
            if (wwi < 0 || wwi >= 28) continue;
#pragma unroll
            for (int r = 0; r < 3; r++) {
                int dd = d + r - 1;
                if (dd < 0 || dd >= 28) continue;
                int nn = hh * WD + wwi * 28 + dd;
                acc += P[((size_t)b * NTOK + nn) * 288 + c] * wv[p * 9 + q * 3 + r];
            }
        }
    }
    y[id] += acc;
}

// ---------------------------------------------------------------------------
// K6: out = y @ proj_w^T + proj_b  — register-tiled GEMM, 64 tok x 48 j tile
// ---------------------------------------------------------------------------
__global__ __launch_bounds__(192) void k_out(
    const float* __restrict__ y, const float* __restrict__ proj_w,
    const float* __restrict__ proj_b, float* __restrict__ out)
{
    __shared__ float xT[96][68];
    __shared__ float wT[96][52];

    const int base = blockIdx.x * 64;
    const int j0 = blockIdx.y * 48;

    for (int it = threadIdx.x; it < 1536; it += 192) {
        int cq = it % 24, t = it / 24;
        float4 v = *(const float4*)(y + (size_t)(base + t) * 96 + cq * 4);
        xT[cq * 4 + 0][t] = v.x; xT[cq * 4 + 1][t] = v.y;
        xT[cq * 4 + 2][t] = v.z; xT[cq * 4 + 3][t] = v.w;
    }
    for (int it = threadIdx.x; it < 1152; it += 192) {
        int cq = it % 24, jl = it / 24;
        float4 v = *(const float4*)(proj_w + (size_t)(j0 + jl) * 96 + cq * 4);
        wT[cq * 4 + 0][jl] = v.x; wT[cq * 4 + 1][jl] = v.y;
        wT[cq * 4 + 2][jl] = v.z; wT[cq * 4 + 3][jl] = v.w;
    }
    __syncthreads();

    const int tq = threadIdx.x & 15;
    const int jq = threadIdx.x >> 4;
    float acc[4][4];
#pragma unroll
    for (int i = 0; i < 4; i++)
#pragma unroll
        for (int jj = 0; jj < 4; jj++) acc[i][jj] = 0.f;

    for (int c = 0; c < 96; c++) {
        float4 xv = *(const float4*)(&xT[c][tq * 4]);
        float4 wv = *(const float4*)(&wT[c][jq * 4]);
        float xa[4] = {xv.x, xv.y, xv.z, xv.w};
        float wa[4] = {wv.x, wv.y, wv.z, wv.w};
#pragma unroll
        for (int i = 0; i < 4; i++)
#pragma unroll
            for (int jj = 0; jj < 4; jj++) acc[i][jj] += xa[i] * wa[jj];
    }

    float4 bias = *(const float4*)(proj_b + j0 + jq * 4);
#pragma unroll
    for (int i = 0; i < 4; i++) {
        int t = base + tq * 4 + i;
        float4 o = make_float4(acc[i][0] + bias.x, acc[i][1] + bias.y,
                               acc[i][2] + bias.z, acc[i][3] + bias.w);
        *(float4*)(out + (size_t)t * 96 + j0 + jq * 4) = o;
    }
}

extern "C" void kernel_launch(void* const* d_in, const int* in_sizes, int n_in,
                              void* d_out, int out_size, void* d_ws, size_t ws_size,
                              hipStream_t stream) {
    const float* x          = (const float*)d_in[0];
    const float* lepe_lin_w = (const float*)d_in[4];
    const float* lepe_lin_b = (const float*)d_in[5];
    const float* lepe_conv_w= (const float*)d_in[6];
    const float* lepe_conv_b= (const float*)d_in[7];
    const float* sr_w       = (const float*)d_in[8];
    const float* sr_b       = (const float*)d_in[9];
    const float* norm_g     = (const float*)d_in[10];
    const float* norm_b     = (const float*)d_in[11];
    const float* q1_w       = (const float*)d_in[12];
    const float* kv1_w      = (const float*)d_in[13];
    const float* q2_w       = (const float*)d_in[14];
    const float* kv2_w      = (const float*)d_in[15];
    const float* proj_w     = (const float*)d_in[16];
    const float* proj_b     = (const float*)d_in[17];

    float* P   = (float*)d_ws;                        // [B*N][288]
    float* k1  = P + (size_t)BB * NTOK * 288;         // [B][3][343][16]
    float* v1  = k1 + (size_t)BB * 3 * NSR * 16;
    float* y   = v1 + (size_t)BB * 3 * NSR * 16;      // [B*N][96]
    float* pa  = y + (size_t)BB * NTOK * 96;          // [686][16][96]
    float* Wt  = pa + (size_t)NSITE * 16 * 96;        // [1536][96] float4

    k_wt<<<576, 256, 0, stream>>>(sr_w, (float4*)Wt);
    k_proj<<<dim3(686, 6), 192, 0, stream>>>(x, lepe_lin_w, lepe_lin_b, q1_w, q2_w, kv2_w, P);
    k_sr_a<<<dim3(86, 16), 128, 0, stream>>>(x, (const float4*)Wt, pa);
    k_sr_b<<<NSITE, 96, 0, stream>>>(pa, sr_b, norm_g, norm_b, kv1_w, k1, v1);
    k_attn1<<<dim3(6, 86), 256, 0, stream>>>(P, k1, v1, y);
    k_attn2<<<768, 192, 0, stream>>>(P, y);
    k_lepe<<<(BB * NTOK * CC + 255) / 256, 256, 0, stream>>>(P, lepe_conv_w, lepe_conv_b, y);
    k_out<<<dim3(686, 2), 192, 0, stream>>>(y, proj_w, proj_b, (float*)d_out);
}